// Round 9
// baseline (2106.588 us; speedup 1.0000x reference)
//
#include <hip/hip_runtime.h>

#define N_NODES 100000
#define NPAD    100096      // 3128 * 32
#define NTILES  3128        // 32-row dst tiles
#define NKEYS   (NTILES * 5)
#define G_GRAPHS 256
#define IN_F 162
#define KPAD0 192
#define HID 128
#define R_REL 5
#define L_LAYERS 2
#define M5 (R_REL * N_NODES)

typedef __attribute__((ext_vector_type(8))) short bf16x8;
typedef __attribute__((ext_vector_type(4))) float f32x4;

__device__ __forceinline__ short f2bf(float f) {
    union { float f; unsigned u; } v; v.f = f;
    unsigned r = (v.u + 0x7fffu + ((v.u >> 16) & 1u)) >> 16;
    return (short)r;
}
__device__ __forceinline__ float bf2f(unsigned short u) {
    union { unsigned u; float f; } v; v.u = ((unsigned)u) << 16;
    return v.f;
}

// ---------------- CSR build: per-(dst,rel) counts + per-(tile,rel) key counts ----------------
__global__ void k_count(const int* e0, const int* e1, const int* e2,
                        const int* e3, const int* e4, int* cnt, int* kcnt, int E) {
    int gid = blockIdx.x * 256 + threadIdx.x;
    if (gid >= R_REL * E) return;
    int r = gid / E, e = gid - r * E;
    const int* ei = (r == 0) ? e0 : (r == 1) ? e1 : (r == 2) ? e2 : (r == 3) ? e3 : e4;
    int dst = ei[E + e];
    atomicAdd(&cnt[r * N_NODES + dst], 1);
    atomicAdd(&kcnt[(dst >> 5) * 5 + r], 1);
}

__global__ void k_invc(const int* __restrict__ cnt, float* __restrict__ invc, int n) {
    int i = blockIdx.x * 256 + threadIdx.x;
    if (i < n) invc[i] = 1.0f / (float)max(cnt[i], 1);
}

// single-block exclusive scan of kcnt -> kstart (+ kcur copy)
__global__ __launch_bounds__(256)
void k_scan_keys(const int* __restrict__ kcnt, int* __restrict__ kstart,
                 int* __restrict__ kcur) {
    __shared__ int ts[256];
    int t = threadIdx.x;
    const int per = (NKEYS + 255) / 256;
    int base = t * per;
    int sum = 0;
    for (int j = 0; j < per; j++) if (base + j < NKEYS) sum += kcnt[base + j];
    ts[t] = sum; __syncthreads();
    for (int o = 1; o < 256; o <<= 1) {
        int x = (t >= o) ? ts[t - o] : 0;
        __syncthreads();
        ts[t] += x;
        __syncthreads();
    }
    int run = ts[t] - sum;
    for (int j = 0; j < per; j++) {
        if (base + j < NKEYS) { kstart[base + j] = run; kcur[base + j] = run; run += kcnt[base + j]; }
    }
    if (t == 255) kstart[NKEYS] = ts[255];
}

// record = (src << 5) | dloc ; mw = 1/deg(dst, rel)
__global__ void k_fillk(const int* e0, const int* e1, const int* e2,
                        const int* e3, const int* e4, int* kcur,
                        const float* __restrict__ invc,
                        int* __restrict__ mrec, float* __restrict__ mw, int E) {
    int gid = blockIdx.x * 256 + threadIdx.x;
    if (gid >= R_REL * E) return;
    int r = gid / E, e = gid - r * E;
    const int* ei = (r == 0) ? e0 : (r == 1) ? e1 : (r == 2) ? e2 : (r == 3) ? e3 : e4;
    int src = ei[e], dst = ei[E + e];
    int pos = atomicAdd(&kcur[(dst >> 5) * 5 + r], 1);
    mrec[pos] = (src << 5) | (dst & 31);
    mw[pos] = invc[r * N_NODES + dst];
}

// ---------------- weight pre-transpose (fp32 -> bf16, [seg][col][Kpad]) ----------------
__global__ void k_tw0(const float* __restrict__ root0, const float* __restrict__ W0,
                      short* __restrict__ out) {
    int gid = blockIdx.x * 256 + threadIdx.x;   // 6*128*192
    if (gid >= 6 * 128 * KPAD0) return;
    int chunk = gid / (128 * KPAD0);
    int rem = gid - chunk * 128 * KPAD0;
    int col = rem / KPAD0;
    int k = rem - col * KPAD0;
    float v = 0.f;
    if (k < IN_F)
        v = (chunk == 0) ? root0[k * HID + col]
                         : W0[((size_t)(chunk - 1) * IN_F + k) * HID + col];
    out[gid] = f2bf(v);
}

__global__ void k_twl(const float* __restrict__ rootl, const float* __restrict__ Wl,
                      short* __restrict__ out) {
    int gid = blockIdx.x * 256 + threadIdx.x;   // 2*6*128*128
    if (gid >= L_LAYERS * 6 * 128 * HID) return;
    int l = gid / (6 * 128 * HID);
    int rem = gid - l * 6 * 128 * HID;
    int chunk = rem / (128 * HID);
    int rem2 = rem - chunk * 128 * HID;
    int col = rem2 / HID;
    int k = rem2 - col * HID;
    float v = (chunk == 0) ? rootl[((size_t)l * HID + k) * HID + col]
                           : Wl[(((size_t)l * R_REL + (chunk - 1)) * HID + k) * HID + col];
    out[gid] = f2bf(v);
}

// ---------------- fused layer v2: breadth-first gather + MFMA ----------------
// H = relu(bias + sum_{seg=0..5} A_seg @ W_seg^T); A_0 = own rows, A_r = per-rel mean of
// gathered rows. Block = 32 dst rows, 4 waves 2x2 (16 rows x 64 cols each).
// A_F32: input is X fp32 [N][162] with SEG=192 zero-padding; else bf16 [NPAD][SEG].
template<int SEG, bool A_F32>
__global__ __launch_bounds__(256)
void layer_fused(const void* __restrict__ Xin_, const short* __restrict__ Wt,
                 const int* __restrict__ kstart, const int* __restrict__ mrec,
                 const float* __restrict__ mw, const float* __restrict__ bias,
                 unsigned short* __restrict__ H) {
    constexpr int SAP = SEG + 4;      // fp32 LDS row stride
    constexpr int SBP = SEG + 8;      // bf16 LDS row stride
    constexpr int C8 = SEG / 8;
    __shared__ float Asf[32 * SAP];
    __shared__ short Bsh[128 * SBP];

    const int tid = threadIdx.x;
    const int tile = blockIdx.x;
    const int row0 = tile * 32;
    const int lane = tid & 63, wv = tid >> 6;
    const int quad = lane >> 4, l16 = lane & 15;
    const int wr0 = (wv >> 1) * 16, wc0 = (wv & 1) * 64;

    float bv[4];
    #pragma unroll
    for (int j = 0; j < 4; j++) bv[j] = bias[wc0 + j * 16 + l16];

    f32x4 acc[4];
    #pragma unroll
    for (int j = 0; j < 4; j++) acc[j] = (f32x4){0.f, 0.f, 0.f, 0.f};

    for (int seg = 0; seg < 6; seg++) {
        __syncthreads();   // prev MFMA done reading Asf/Bsh
        // ---- fill Asf ----
        if (seg == 0) {
            if (A_F32) {
                const float* X = (const float*)Xin_;
                for (int c = tid; c < 32 * (SEG / 4); c += 256) {
                    int r = c / (SEG / 4), c4 = (c - r * (SEG / 4)) * 4;
                    int grow = row0 + r;
                    f32x4 v = (f32x4){0.f, 0.f, 0.f, 0.f};
                    if (grow < N_NODES) {
                        #pragma unroll
                        for (int j = 0; j < 4; j++)
                            if (c4 + j < IN_F) v[j] = X[(size_t)grow * IN_F + c4 + j];
                    }
                    *(f32x4*)&Asf[r * SAP + c4] = v;
                }
            } else {
                const unsigned short* X = (const unsigned short*)Xin_;
                for (int c = tid; c < 32 * C8; c += 256) {
                    int r = c / C8, c8 = (c - r * C8) * 8;
                    bf16x8 v = *(const bf16x8*)&X[(size_t)(row0 + r) * SEG + c8];
                    float* dp = &Asf[r * SAP + c8];
                    #pragma unroll
                    for (int j = 0; j < 8; j++) dp[j] = bf2f((unsigned short)v[j]);
                }
            }
        } else {
            for (int c = tid; c < 32 * (SEG / 4); c += 256) {
                int r = c / (SEG / 4), c4 = (c - r * (SEG / 4)) * 4;
                *(f32x4*)&Asf[r * SAP + c4] = (f32x4){0.f, 0.f, 0.f, 0.f};
            }
        }
        // ---- stage Bsh ----
        const short* Wc = Wt + (size_t)seg * 128 * SEG;
        for (int c = tid; c < 128 * C8; c += 256) {
            int r = c / C8, c8 = (c - r * C8) * 8;
            *(bf16x8*)&Bsh[r * SBP + c8] = *(const bf16x8*)&Wc[r * SEG + c8];
        }
        __syncthreads();
        // ---- breadth-first gather for this (tile, relation) ----
        if (seg >= 1) {
            int key = tile * 5 + (seg - 1);
            int ks = kstart[key], ke = kstart[key + 1];
            for (int base = ks + wv * 8; base < ke; base += 32) {
                int nb = min(8, ke - base);
                int rec = 0; float wgt = 0.f;
                if (lane < nb) { rec = mrec[base + lane]; wgt = mw[base + lane]; }
                // phase 1: issue ALL row loads (independent, 8-deep in flight)
                float2 vf[8]; float v3[8]; unsigned vu[8]; unsigned short t3[8];
                int dl[8]; float wj[8];
                #pragma unroll
                for (int j = 0; j < 8; j++) {
                    dl[j] = 0; wj[j] = 0.f;
                    if (A_F32) { vf[j] = make_float2(0.f, 0.f); v3[j] = 0.f; }
                    else { vu[j] = 0u; t3[j] = 0; }
                    if (j < nb) {
                        int rj = __shfl(rec, j, 64);
                        wj[j] = __shfl(wgt, j, 64);
                        dl[j] = rj & 31;
                        int src = rj >> 5;
                        if (A_F32) {
                            const float* rp = (const float*)Xin_ + (size_t)src * IN_F;
                            vf[j] = *(const float2*)(rp + 2 * lane);
                            if (128 + lane < IN_F) v3[j] = rp[128 + lane];
                        } else {
                            const unsigned short* rp = (const unsigned short*)Xin_ + (size_t)src * SEG;
                            vu[j] = *(const unsigned*)&rp[2 * lane];
                            if (SEG > 128) t3[j] = rp[128 + lane];
                        }
                    }
                }
                // phase 2: LDS atomic accumulate
                #pragma unroll
                for (int j = 0; j < 8; j++) {
                    if (j < nb) {
                        float* arow = &Asf[dl[j] * SAP];
                        if (A_F32) {
                            atomicAdd(&arow[2 * lane],     vf[j].x * wj[j]);
                            atomicAdd(&arow[2 * lane + 1], vf[j].y * wj[j]);
                            if (128 + lane < IN_F) atomicAdd(&arow[128 + lane], v3[j] * wj[j]);
                        } else {
                            atomicAdd(&arow[2 * lane],     bf2f((unsigned short)(vu[j] & 0xffff)) * wj[j]);
                            atomicAdd(&arow[2 * lane + 1], bf2f((unsigned short)(vu[j] >> 16)) * wj[j]);
                            if (SEG > 128) atomicAdd(&arow[128 + lane], bf2f(t3[j]) * wj[j]);
                        }
                    }
                }
            }
            __syncthreads();
        }
        // ---- MFMA K-loop over this segment ----
        #pragma unroll
        for (int kb = 0; kb < SEG / 32; kb++) {
            const float* ap = &Asf[(wr0 + l16) * SAP + kb * 32 + quad * 8];
            f32x4 a0 = *(const f32x4*)ap;
            f32x4 a1 = *(const f32x4*)(ap + 4);
            bf16x8 af;
            #pragma unroll
            for (int j = 0; j < 4; j++) { af[j] = f2bf(a0[j]); af[4 + j] = f2bf(a1[j]); }
            #pragma unroll
            for (int j = 0; j < 4; j++) {
                bf16x8 bf8 = *(const bf16x8*)&Bsh[(wc0 + j * 16 + l16) * SBP + kb * 32 + quad * 8];
                acc[j] = __builtin_amdgcn_mfma_f32_16x16x32_bf16(af, bf8, acc[j], 0, 0, 0);
            }
        }
    }
    __syncthreads();
    // ---- epilogue: bias + relu -> Bsh (bf16) -> coalesced stores ----
    #pragma unroll
    for (int j = 0; j < 4; j++)
        #pragma unroll
        for (int reg = 0; reg < 4; reg++) {
            float v = fmaxf(acc[j][reg] + bv[j], 0.f);
            Bsh[(wr0 + quad * 4 + reg) * SBP + wc0 + j * 16 + l16] = f2bf(v);
        }
    __syncthreads();
    for (int c = tid; c < 32 * 16; c += 256) {
        int r = c >> 4, c8 = (c & 15) * 8;
        bf16x8 v = *(const bf16x8*)&Bsh[r * SBP + c8];
        *(bf16x8*)&H[(size_t)(row0 + r) * HID + c8] = v;
    }
}

// ---------------- readout ----------------
__global__ __launch_bounds__(128)
void k_pool(const unsigned short* __restrict__ h, const int* __restrict__ batch,
            float* __restrict__ pooled) {
    int c = threadIdx.x;
    int start = blockIdx.x * 128;
    if (start >= N_NODES) return;
    int end = min(start + 128, N_NODES);
    int g = batch[start];
    float s = 0.f;
    for (int i = start; i < end; i++) {
        int gi = batch[i];
        if (gi != g) { atomicAdd(&pooled[g * HID + c], s); s = 0.f; g = gi; }
        s += bf2f(h[(size_t)i * HID + c]);
    }
    atomicAdd(&pooled[g * HID + c], s);
}

__device__ int lower_bound_i(const int* a, int n, int v) {
    int lo = 0, hi = n;
    while (lo < hi) {
        int mid = (lo + hi) >> 1;
        if (a[mid] < v) lo = mid + 1; else hi = mid;
    }
    return lo;
}

__global__ __launch_bounds__(128)
void k_mlp(const float* __restrict__ pooled, const int* __restrict__ batch,
           const float* __restrict__ Wc1, const float* __restrict__ bc1,
           const float* __restrict__ Wc2, const float* __restrict__ bc2,
           const float* __restrict__ Wc3, const float* __restrict__ bc3,
           float* __restrict__ out) {
    int g = blockIdx.x;
    int c = threadIdx.x;
    __shared__ int range[2];
    if (c == 0) range[0] = lower_bound_i(batch, N_NODES, g);
    if (c == 1) range[1] = lower_bound_i(batch, N_NODES, g + 1);
    __syncthreads();
    float denom = fmaxf((float)(range[1] - range[0]), 1.0f);
    __shared__ float row[HID], h1[HID], h2[HID];
    row[c] = pooled[g * HID + c] / denom;
    __syncthreads();
    float acc = bc1[c];
    for (int k = 0; k < HID; k++) acc += row[k] * Wc1[k * HID + c];
    h1[c] = fmaxf(acc, 0.f);
    __syncthreads();
    acc = bc2[c];
    for (int k = 0; k < HID; k++) acc += h1[k] * Wc2[k * HID + c];
    h2[c] = fmaxf(acc, 0.f);
    __syncthreads();
    float t = h2[c] * Wc3[c];
    for (int off = 32; off > 0; off >>= 1) t += __shfl_down(t, off, 64);
    __shared__ float part[2];
    if ((c & 63) == 0) part[c >> 6] = t;
    __syncthreads();
    if (c == 0) out[g] = part[0] + part[1] + bc3[0];
}

// ---------------- launcher ----------------
extern "C" void kernel_launch(void* const* d_in, const int* in_sizes, int n_in,
                              void* d_out, int out_size, void* d_ws, size_t ws_size,
                              hipStream_t stream) {
    const float* X     = (const float*)d_in[0];
    const int*   batch = (const int*)d_in[1];
    const int*   e0 = (const int*)d_in[2];
    const int*   e1 = (const int*)d_in[3];
    const int*   e2 = (const int*)d_in[4];
    const int*   e3 = (const int*)d_in[5];
    const int*   e4 = (const int*)d_in[6];
    const float* W0    = (const float*)d_in[7];
    const float* root0 = (const float*)d_in[8];
    const float* b0    = (const float*)d_in[9];
    const float* Wl    = (const float*)d_in[10];
    const float* rootl = (const float*)d_in[11];
    const float* bl    = (const float*)d_in[12];
    const float* Wc1   = (const float*)d_in[13];
    const float* bc1   = (const float*)d_in[14];
    const float* Wc2   = (const float*)d_in[15];
    const float* bc2   = (const float*)d_in[16];
    const float* Wc3   = (const float*)d_in[17];
    const float* bc3   = (const float*)d_in[18];
    const int E = in_sizes[2] / 2;
    const int NE = R_REL * E;

    char* base = (char*)d_ws;
    size_t o = 0;
    auto carve = [&](size_t bytes) -> char* {
        char* p = base + o;
        o = (o + bytes + 255) & ~(size_t)255;
        return p;
    };
    unsigned short* hA   = (unsigned short*)carve((size_t)NPAD * HID * 2);
    unsigned short* hB   = (unsigned short*)carve((size_t)NPAD * HID * 2);
    int*   cnt    = (int*)carve((size_t)M5 * 4);
    float* invc   = (float*)carve((size_t)M5 * 4);
    int*   kcnt   = (int*)carve((size_t)NKEYS * 4);
    int*   kstart = (int*)carve((size_t)(NKEYS + 1) * 4);
    int*   kcur   = (int*)carve((size_t)NKEYS * 4);
    int*   mrec   = (int*)carve((size_t)NE * 4);
    float* mw     = (float*)carve((size_t)NE * 4);
    float* pooled = (float*)carve((size_t)G_GRAPHS * HID * 4);
    short* Wt0    = (short*)carve((size_t)6 * 128 * KPAD0 * 2);
    short* Wtl    = (short*)carve((size_t)L_LAYERS * 6 * 128 * HID * 2);

    // ---- CSR build + weight prep ----
    hipMemsetAsync(cnt, 0, (size_t)M5 * 4, stream);
    hipMemsetAsync(kcnt, 0, (size_t)NKEYS * 4, stream);
    hipMemsetAsync(pooled, 0, (size_t)G_GRAPHS * HID * 4, stream);
    int eg = (NE + 255) / 256;
    k_count<<<eg, 256, 0, stream>>>(e0, e1, e2, e3, e4, cnt, kcnt, E);
    k_invc<<<(M5 + 255) / 256, 256, 0, stream>>>(cnt, invc, M5);
    k_scan_keys<<<1, 256, 0, stream>>>(kcnt, kstart, kcur);
    k_fillk<<<eg, 256, 0, stream>>>(e0, e1, e2, e3, e4, kcur, invc, mrec, mw, E);
    k_tw0<<<(6 * 128 * KPAD0 + 255) / 256, 256, 0, stream>>>(root0, W0, Wt0);
    k_twl<<<(L_LAYERS * 6 * 128 * HID + 255) / 256, 256, 0, stream>>>(rootl, Wl, Wtl);

    // ---- fused layers ----
    layer_fused<KPAD0, true><<<NTILES, 256, 0, stream>>>(X, Wt0, kstart, mrec, mw, b0, hA);
    layer_fused<HID, false><<<NTILES, 256, 0, stream>>>(hA, Wtl, kstart, mrec, mw, bl, hB);
    layer_fused<HID, false><<<NTILES, 256, 0, stream>>>(hB, Wtl + (size_t)6 * 128 * HID,
                                                        kstart, mrec, mw, bl + HID, hA);

    // ---- readout ----
    k_pool<<<(N_NODES + 127) / 128, 128, 0, stream>>>(hA, batch, pooled);
    k_mlp<<<G_GRAPHS, 128, 0, stream>>>(pooled, batch, Wc1, bc1, Wc2, bc2, Wc3, bc3, (float*)d_out);
}